// Round 2
// baseline (392.928 us; speedup 1.0000x reference)
//
#include <hip/hip_runtime.h>
#include <hip/hip_bf16.h>
#include <stdint.h>
#include <math.h>

#define NROWS 16384
#define DHALF 384
#define DFULL 768
#define ROWB  384      // bytes per fp4 row: 768 elems * 4 bit
#define EPSF  1e-8f
#define QSCALE 64.0f   // N(0,0.036)*64 -> N(0,2.3): centered in e2m1 range +-6

typedef __attribute__((ext_vector_type(4)))  float f32x4;
typedef __attribute__((ext_vector_type(4)))  int   int4v;
typedef __attribute__((ext_vector_type(8)))  int   int8v;

// ---- async global->LDS, 16B per lane (wave-uniform base + lane*16) ----
__device__ __forceinline__ void async_copy16(const void* gptr, void* lptr) {
    __builtin_amdgcn_global_load_lds(
        (const __attribute__((address_space(1))) unsigned int*)gptr,
        (__attribute__((address_space(3))) unsigned int*)lptr,
        16, 0, 0);
}

// counted-vmcnt barrier (T4): wait until <=N vector-mem ops outstanding,
// then barrier. N=4 keeps the newest stage's 4 global_load_lds in flight
// ACROSS the barrier (the compiler's __syncthreads would drain vmcnt(0)).
#define PIPE_SYNC(N)                                            \
    do {                                                        \
        asm volatile("s_waitcnt vmcnt(" #N ")" ::: "memory");   \
        __builtin_amdgcn_s_barrier();                           \
        __builtin_amdgcn_sched_barrier(0);                      \
    } while (0)

// monotone u32 from raw float bits (order-preserving for all finite floats)
__device__ __forceinline__ unsigned mono_bits(unsigned u) {
    return u ^ ((unsigned)(((int)u) >> 31) | 0x80000000u);
}

// float key: clear low 6 mantissa bits, embed 6-bit index. IEEE compare
// order == value order (perturbation <= 2^-18 relative, harmless after
// fp4 quantization); winner carries its index. v_and_or_b32 = 1 VALU op.
__device__ __forceinline__ float kf(float v, unsigned idx) {
    return __uint_as_float((__float_as_uint(v) & ~63u) | idx);
}

// float max with a DPP row_ror'd copy (16-lane row, pure VALU)
template <int CTRL>
__device__ __forceinline__ float fmax_ror(float v) {
    float t = __int_as_float(__builtin_amdgcn_update_dpp(
        0, __float_as_int(v), CTRL, 0xF, 0xF, false));
    return fmaxf(v, t);
}

// fp4 e2m1 encode, round-to-nearest: values {0,.5,1,1.5,2,3,4,6} (+sign)
__device__ __forceinline__ unsigned enc_fp4(float v) {
    float a = fabsf(v);
    unsigned c = (unsigned)(a >= 0.25f) + (a >= 0.75f) + (a >= 1.25f) +
                 (a >= 1.75f) + (a >= 2.5f) + (a >= 3.5f) + (a >= 5.0f);
    return c | (v < 0.0f ? 8u : 0u);
}

// fp32 -> bf16 bits, round-to-nearest-even (no NaN inputs here)
__device__ __forceinline__ unsigned f2bf(float f) {
    unsigned u = __float_as_uint(f);
    return (u + (((u >> 16) & 1u) + 0x7fffu)) >> 16;
}
__device__ __forceinline__ float bf_lo(unsigned w) {   // low bf16 of packed pair
    return __uint_as_float(w << 16);
}
__device__ __forceinline__ float bf_hi(unsigned w) {   // high bf16
    return __uint_as_float(w & 0xffff0000u);
}

// ---------------------------------------------------------------------
// Kernel 1: per-row L2 norm over concat(a,b); write fp4-e2m1 nibbles of
// (x_norm * 64). Optionally also write bf16 normalized rows (xb) for
// the loss gather. Zeroes best[row].
// ---------------------------------------------------------------------
__global__ __launch_bounds__(256) void normalize_kernel(
    const float* __restrict__ a, const float* __restrict__ b,
    unsigned char* __restrict__ xq, float* __restrict__ invn,
    unsigned long long* __restrict__ best,
    unsigned* __restrict__ xb) {           // nullable
    int wave = threadIdx.x >> 6;
    int lane = threadIdx.x & 63;
    int row  = blockIdx.x * 4 + wave;

    const float2* pa = (const float2*)(a + (size_t)row * DHALF);  // 192 pairs
    const float2* pb = (const float2*)(b + (size_t)row * DHALF);

    float2 va[3], vb[3];
    float s = 0.0f;
#pragma unroll
    for (int it = 0; it < 3; ++it) {
        va[it] = pa[lane + 64 * it];
        s += va[it].x * va[it].x + va[it].y * va[it].y;
    }
#pragma unroll
    for (int it = 0; it < 3; ++it) {
        vb[it] = pb[lane + 64 * it];
        s += vb[it].x * vb[it].x + vb[it].y * vb[it].y;
    }
#pragma unroll
    for (int d = 1; d < 64; d <<= 1) s += __shfl_xor(s, d, 64);

    float inv = 1.0f / fmaxf(sqrtf(s), EPSF);
    if (lane == 0) { invn[row] = inv; best[row] = 0ull; }
    float qs = inv * QSCALE;

    unsigned char* px = xq + (size_t)row * ROWB;
#pragma unroll
    for (int it = 0; it < 3; ++it)
        px[lane + 64 * it] =
            (unsigned char)(enc_fp4(va[it].x * qs) | (enc_fp4(va[it].y * qs) << 4));
#pragma unroll
    for (int it = 0; it < 3; ++it)
        px[192 + lane + 64 * it] =
            (unsigned char)(enc_fp4(vb[it].x * qs) | (enc_fp4(vb[it].y * qs) << 4));

    if (xb) {   // uniform branch
        unsigned* pw = xb + (size_t)row * (DFULL / 2);   // 384 packed pairs
#pragma unroll
        for (int it = 0; it < 3; ++it)
            pw[lane + 64 * it] =
                f2bf(va[it].x * inv) | (f2bf(va[it].y * inv) << 16);
#pragma unroll
        for (int it = 0; it < 3; ++it)
            pw[192 + lane + 64 * it] =
                f2bf(vb[it].x * inv) | (f2bf(vb[it].y * inv) << 16);
    }
}

// ---------------------------------------------------------------------
// Kernel 2: scaled dots via MX-fp4 16x16x128 MFMA, 128x128 tile, BK=128
// elems = 64 B/row, upper-triangle blocks (symmetry). R12: 3-buffer LDS
// pipeline staged 2 K-steps ahead with counted s_waitcnt vmcnt(4) at
// each barrier (T3/T4) — loads stay in flight across barriers instead
// of the compiler's vmcnt(0) drain. Persistent int8v fragments (high
// half zeroed once; fp4 fmt ignores v[4:7]).
// ---------------------------------------------------------------------
__global__ __launch_bounds__(256, 3) void argmax_kernel(
    const unsigned char* __restrict__ xq,
    unsigned long long* __restrict__ best) {
    __shared__ unsigned char As[3][128 * 64];
    __shared__ unsigned char Bs[3][128 * 64];

    // decode upper-triangle pair: k -> (rb <= cb)
    int k = blockIdx.x;
    int i = (int)((sqrtf(8.0f * (float)k + 1.0f) - 1.0f) * 0.5f);
    while ((i + 1) * (i + 2) / 2 <= k) ++i;
    while (i * (i + 1) / 2 > k) --i;
    int cb = i;
    int rb = k - i * (i + 1) / 2;   // rb <= cb
    int r0 = rb * 128, c0 = cb * 128;

    int tid  = threadIdx.x;
    int wave = tid >> 6, lane = tid & 63;
    int wr = wave >> 1, wc = wave & 1;
    int quad = lane >> 4, l15 = lane & 15;

    f32x4 acc[4][4] = {};
    const int SC = 0x7f7f7f7f;      // e8m0 scales = 1.0 in every byte

    // staging pointers: 2 rounds x 256 threads cover 512 granules/tile
    const unsigned char* gA[2];
    const unsigned char* gB[2];
    int lofs[2];
#pragma unroll
    for (int r2 = 0; r2 < 2; ++r2) {
        int idx = r2 * 256 + tid;          // 0..511
        int r   = idx >> 2;                // 0..127
        int s   = idx & 3;                 // dst slot
        int g   = s ^ ((r ^ (r >> 2)) & 3);   // swizzled source granule
        gA[r2] = xq + (size_t)(r0 + r) * ROWB + (g << 4);
        gB[r2] = xq + (size_t)(c0 + r) * ROWB + (g << 4);
        lofs[r2] = idx * 16;
    }

    // fragment LDS offsets (loop-invariant)
    int s0 = ((quad ^ ((l15 ^ (l15 >> 2)) & 3)) << 4);
    int aof[4], bof[4];
#pragma unroll
    for (int t = 0; t < 4; ++t) {
        aof[t] = (wr * 64 + t * 16 + l15) * 64 + s0;
        bof[t] = (wc * 64 + t * 16 + l15) * 64 + s0;
    }

    // persistent operand tuples: high halves zeroed ONCE (fp4 operand
    // format reads only v[0:3]; re-zeroing per K-step was pure VALU waste)
    int8v a8  = {};
    int8v bfr[4] = {};

    auto stage = [&](int k0b, int buf) {
        async_copy16(gA[0] + k0b, &As[buf][lofs[0]]);
        async_copy16(gA[1] + k0b, &As[buf][lofs[1]]);
        async_copy16(gB[0] + k0b, &Bs[buf][lofs[0]]);
        async_copy16(gB[1] + k0b, &Bs[buf][lofs[1]]);
    };
    auto compute = [&](int buf) {
        const unsigned char* Ab = As[buf];
        const unsigned char* Bb = Bs[buf];
#pragma unroll
        for (int t = 0; t < 4; ++t)
            *(int4v*)&bfr[t] = *(const int4v*)(&Bb[bof[t]]);
#pragma unroll
        for (int ti = 0; ti < 4; ++ti) {
            *(int4v*)&a8 = *(const int4v*)(&Ab[aof[ti]]);
#pragma unroll
            for (int tj = 0; tj < 4; ++tj)
                acc[ti][tj] = __builtin_amdgcn_mfma_scale_f32_16x16x128_f8f6f4(
                    a8, bfr[tj], acc[ti][tj], 4, 4, 0, SC, 0, SC);
        }
    };

    // ---- 6 K-steps, 3 buffers, staged 2 ahead, counted vmcnt ----
    // step t computes buf t%3; stage(k) issues 4 copies/thread.
    stage(0, 0);
    stage(64, 1);
    PIPE_SYNC(4);            // buf0 landed; buf1's 4 copies still in flight

    stage(128, 2); compute(0);
    PIPE_SYNC(4);            // buf1 landed; buf2 in flight
    stage(192, 0); compute(1);
    PIPE_SYNC(4);            // buf2 landed; buf0(k192) in flight
    stage(256, 1); compute(2);
    PIPE_SYNC(4);            // buf0 landed; buf1(k256) in flight
    stage(320, 2); compute(0);
    PIPE_SYNC(4);            // buf1 landed; buf2(k320) in flight
    compute(1);
    PIPE_SYNC(0);            // drain: buf2 landed
    compute(2);              // last tile; epilogue is register-only

    int rbase = r0 + wr * 64, cbase = c0 + wc * 64;

    // Diagonal mask: only possible in diagonal blocks, and only in waves
    // with wr==wc. Hoisted here so the hot epilogue below is mask-free.
    if (rb == cb && wr == wc) {
#pragma unroll
        for (int ti = 0; ti < 4; ++ti)
#pragma unroll
            for (int reg = 0; reg < 4; ++reg)
                if (l15 == quad * 4 + reg)
                    acc[ti][ti][reg] = -1.0e30f;
    }

    // Row-direction: float key = (bits & ~63) | (tj<<4 | l15); fmax + DPP
    // reduce; monotone transform applied once to the 16-lane winner.
#pragma unroll
    for (int ti = 0; ti < 4; ++ti) {
#pragma unroll
        for (int reg = 0; reg < 4; ++reg) {
            float f0 = kf(acc[ti][0][reg], (unsigned)((0 << 4) | l15));
            float f1 = kf(acc[ti][1][reg], (unsigned)((1 << 4) | l15));
            float f2 = kf(acc[ti][2][reg], (unsigned)((2 << 4) | l15));
            float f3 = kf(acc[ti][3][reg], (unsigned)((3 << 4) | l15));
            float fk = fmaxf(fmaxf(f0, f1), fmaxf(f2, f3));
            fk = fmax_ror<0x121>(fk);   // ror 1
            fk = fmax_ror<0x122>(fk);   // ror 2
            fk = fmax_ror<0x124>(fk);   // ror 4
            fk = fmax_ror<0x128>(fk);   // ror 8
            if (l15 == 0) {
                unsigned kb = __float_as_uint(fk);
                int grow = rbase + ti * 16 + quad * 4 + reg;
                int col  = cbase + (int)(((kb >> 4) & 3u) * 16u + (kb & 15u));
                unsigned long long gk =
                    ((unsigned long long)(mono_bits(kb) & ~63u) << 32) |
                    (unsigned)col;
                atomicMax(&best[grow], gk);
            }
        }
    }

    // Column-direction (off-diagonal blocks): 16 in-lane candidates,
    // then 2 cross-lane maxes; key idx = (ti<<4)|(quad<<2)|reg.
    if (rb != cb) {
#pragma unroll
        for (int tj = 0; tj < 4; ++tj) {
            float fk = kf(acc[0][tj][0], (unsigned)(quad << 2));
#pragma unroll
            for (int ti = 0; ti < 4; ++ti)
#pragma unroll
                for (int reg = 0; reg < 4; ++reg)
                    if (ti | reg)
                        fk = fmaxf(fk, kf(acc[ti][tj][reg],
                                (unsigned)((ti << 4) | (quad << 2) | reg)));
            fk = fmaxf(fk, __shfl_xor(fk, 16, 64));
            fk = fmaxf(fk, __shfl_xor(fk, 32, 64));
            if (quad == 0) {
                unsigned kb = __float_as_uint(fk);
                int grow = rbase + (int)(((kb >> 4) & 3u) * 16u +
                                         ((kb >> 2) & 3u) * 4u + (kb & 3u));
                int gcol = cbase + tj * 16 + l15;
                unsigned long long gk =
                    ((unsigned long long)(mono_bits(kb) & ~63u) << 32) |
                    (unsigned)grow;
                atomicMax(&best[gcol], gk);
            }
        }
    }
}

// ---------------------------------------------------------------------
// Kernel 3a: loss from bf16 normalized rows (50 MB vs 100 MB fp32 path)
// ---------------------------------------------------------------------
__global__ __launch_bounds__(256) void loss_bf16_kernel(
    const unsigned* __restrict__ xb,
    const unsigned long long* __restrict__ best,
    float* __restrict__ terms) {
    int wave = threadIdx.x >> 6;
    int lane = threadIdx.x & 63;
    int row  = blockIdx.x * 4 + wave;

    int j = (int)(best[row] & 0xffffffffull);
    const uint2* pi = (const uint2*)(xb + (size_t)row * (DFULL / 2));
    const uint2* pj = (const uint2*)(xb + (size_t)j   * (DFULL / 2));

    float s = 0.0f;
#pragma unroll
    for (int it = 0; it < 3; ++it) {
        int kk = lane + 64 * it;
        uint2 wi = pi[kk], wj = pj[kk];
        float d0 = bf_lo(wi.x) - bf_lo(wj.x) + EPSF;
        float d1 = bf_hi(wi.x) - bf_hi(wj.x) + EPSF;
        float d2 = bf_lo(wi.y) - bf_lo(wj.y) + EPSF;
        float d3 = bf_hi(wi.y) - bf_hi(wj.y) + EPSF;
        s += d0 * d0 + d1 * d1 + d2 * d2 + d3 * d3;
    }
#pragma unroll
    for (int d = 1; d < 64; d <<= 1) s += __shfl_xor(s, d, 64);

    if (lane == 0) terms[row] = logf(sqrtf(s) + EPSF);
}

// ---------------------------------------------------------------------
// Kernel 3b: fallback — loss from fp32 originals (if ws too small)
// ---------------------------------------------------------------------
__global__ __launch_bounds__(256) void loss_kernel(
    const float* __restrict__ a, const float* __restrict__ b,
    const float* __restrict__ invn,
    const unsigned long long* __restrict__ best,
    float* __restrict__ terms) {
    int wave = threadIdx.x >> 6;
    int lane = threadIdx.x & 63;
    int row  = blockIdx.x * 4 + wave;

    int j = (int)(best[row] & 0xffffffffull);
    float ii = invn[row], ij = invn[j];

    const float2* pai = (const float2*)(a + (size_t)row * DHALF);
    const float2* pbi = (const float2*)(b + (size_t)row * DHALF);
    const float2* paj = (const float2*)(a + (size_t)j * DHALF);
    const float2* pbj = (const float2*)(b + (size_t)j * DHALF);

    float s = 0.0f;
#pragma unroll
    for (int it = 0; it < 3; ++it) {
        int kk = lane + 64 * it;
        float2 di = pai[kk], dj = paj[kk];
        float dx = di.x * ii - dj.x * ij + EPSF;
        float dy = di.y * ii - dj.y * ij + EPSF;
        s += dx * dx + dy * dy;
    }
#pragma unroll
    for (int it = 0; it < 3; ++it) {
        int kk = lane + 64 * it;
        float2 di = pbi[kk], dj = pbj[kk];
        float dx = di.x * ii - dj.x * ij + EPSF;
        float dy = di.y * ii - dj.y * ij + EPSF;
        s += dx * dx + dy * dy;
    }
#pragma unroll
    for (int d = 1; d < 64; d <<= 1) s += __shfl_xor(s, d, 64);

    if (lane == 0) terms[row] = logf(sqrtf(s) + EPSF);
}

// ---------------------------------------------------------------------
// Kernel 4: single-block tree reduction of terms -> out[0] = -mean
// ---------------------------------------------------------------------
__global__ __launch_bounds__(1024) void reduce_kernel(
    const float* __restrict__ terms, float* __restrict__ out) {
    __shared__ float partial[16];
    int tid = threadIdx.x;
    float s = 0.0f;
#pragma unroll
    for (int it = 0; it < NROWS / 1024; ++it) s += terms[tid + 1024 * it];
#pragma unroll
    for (int d = 1; d < 64; d <<= 1) s += __shfl_xor(s, d, 64);
    if ((tid & 63) == 0) partial[tid >> 6] = s;
    __syncthreads();
    if (tid < 16) {
        s = partial[tid];
#pragma unroll
        for (int d = 1; d < 16; d <<= 1) s += __shfl_xor(s, d, 16);
        if (tid == 0) out[0] = -s * (1.0f / (float)NROWS);
    }
}

// ---------------------------------------------------------------------
extern "C" void kernel_launch(void* const* d_in, const int* in_sizes, int n_in,
                              void* d_out, int out_size, void* d_ws, size_t ws_size,
                              hipStream_t stream) {
    const float* a = (const float*)d_in[0];
    const float* b = (const float*)d_in[1];
    float* out = (float*)d_out;

    char* ws = (char*)d_ws;
    unsigned char* xq = (unsigned char*)ws;                                    // 6291456 B
    unsigned long long* best = (unsigned long long*)(ws + 6291456);            // 131072 B
    float* invn  = (float*)(ws + 6291456 + 131072);                            // 65536 B
    float* terms = (float*)(ws + 6291456 + 131072 + 65536);                    // 65536 B
    unsigned* xb = (unsigned*)(ws + 6291456 + 131072 + 65536 + 65536);         // 25165824 B
    const size_t need_xb = 6291456ull + 131072 + 65536 + 65536 + 25165824;
    const bool use_xb = ws_size >= need_xb;   // constant across calls

    const int NTILE = NROWS / 128;                     // 128
    const int NBLK  = NTILE * (NTILE + 1) / 2;         // 8256

    normalize_kernel<<<NROWS / 4, 256, 0, stream>>>(
        a, b, xq, invn, best, use_xb ? xb : (unsigned*)nullptr);
    argmax_kernel<<<NBLK, 256, 0, stream>>>(xq, best);
    if (use_xb)
        loss_bf16_kernel<<<NROWS / 4, 256, 0, stream>>>(xb, best, terms);
    else
        loss_kernel<<<NROWS / 4, 256, 0, stream>>>(a, b, invn, best, terms);
    reduce_kernel<<<1, 1024, 0, stream>>>(terms, out);
}

// Round 3
// 392.065 us; speedup vs baseline: 1.0022x; 1.0022x over previous
//
#include <hip/hip_runtime.h>
#include <hip/hip_bf16.h>
#include <stdint.h>
#include <math.h>

#define NROWS 16384
#define DHALF 384
#define DFULL 768
#define ROWB  384      // bytes per fp4 row: 768 elems * 4 bit
#define EPSF  1e-8f
#define QSCALE 64.0f   // N(0,0.036)*64 -> N(0,2.3): centered in e2m1 range +-6

typedef __attribute__((ext_vector_type(4)))  float f32x4;
typedef __attribute__((ext_vector_type(4)))  int   int4v;
typedef __attribute__((ext_vector_type(8)))  int   int8v;

// ---- async global->LDS, 16B per lane (wave-uniform base + lane*16) ----
__device__ __forceinline__ void async_copy16(const void* gptr, void* lptr) {
    __builtin_amdgcn_global_load_lds(
        (const __attribute__((address_space(1))) unsigned int*)gptr,
        (__attribute__((address_space(3))) unsigned int*)lptr,
        16, 0, 0);
}

// counted-vmcnt barrier (T4): wait until <=N vector-mem ops outstanding,
// then barrier. N=4 keeps the newest stage's 4 global_load_lds in flight
// ACROSS the barrier (the compiler's __syncthreads would drain vmcnt(0)).
#define PIPE_SYNC(N)                                            \
    do {                                                        \
        asm volatile("s_waitcnt vmcnt(" #N ")" ::: "memory");   \
        __builtin_amdgcn_s_barrier();                           \
        __builtin_amdgcn_sched_barrier(0);                      \
    } while (0)

// monotone u32 from raw float bits (order-preserving for all finite floats)
__device__ __forceinline__ unsigned mono_bits(unsigned u) {
    return u ^ ((unsigned)(((int)u) >> 31) | 0x80000000u);
}

// float key: clear low 6 mantissa bits, embed 6-bit index. IEEE compare
// order == value order (perturbation <= 2^-18 relative, harmless after
// fp4 quantization); winner carries its index. v_and_or_b32 = 1 VALU op.
__device__ __forceinline__ float kf(float v, unsigned idx) {
    return __uint_as_float((__float_as_uint(v) & ~63u) | idx);
}

// float max with a DPP row_ror'd copy (16-lane row, pure VALU)
template <int CTRL>
__device__ __forceinline__ float fmax_ror(float v) {
    float t = __int_as_float(__builtin_amdgcn_update_dpp(
        0, __float_as_int(v), CTRL, 0xF, 0xF, false));
    return fmaxf(v, t);
}

// fp4 e2m1 encode, round-to-nearest: values {0,.5,1,1.5,2,3,4,6} (+sign)
__device__ __forceinline__ unsigned enc_fp4(float v) {
    float a = fabsf(v);
    unsigned c = (unsigned)(a >= 0.25f) + (a >= 0.75f) + (a >= 1.25f) +
                 (a >= 1.75f) + (a >= 2.5f) + (a >= 3.5f) + (a >= 5.0f);
    return c | (v < 0.0f ? 8u : 0u);
}

// fp32 -> bf16 bits, round-to-nearest-even (no NaN inputs here)
__device__ __forceinline__ unsigned f2bf(float f) {
    unsigned u = __float_as_uint(f);
    return (u + (((u >> 16) & 1u) + 0x7fffu)) >> 16;
}
__device__ __forceinline__ float bf_lo(unsigned w) {   // low bf16 of packed pair
    return __uint_as_float(w << 16);
}
__device__ __forceinline__ float bf_hi(unsigned w) {   // high bf16
    return __uint_as_float(w & 0xffff0000u);
}

// fp4 operand: HW reads only v[0:3] of the 8-reg tuple (cbsz/blgp=4).
// High half is compile-time zero. BY-VALUE return — SROA keeps this in
// VGPRs. (R12 lesson: writing through a type-punned pointer into a
// persistent int8v local defeats SROA -> scratch -> 1.1 GB HBM traffic.)
__device__ __forceinline__ int8v to8(int4v q) {
    int8v r;
    r[0] = q[0]; r[1] = q[1]; r[2] = q[2]; r[3] = q[3];
    r[4] = 0; r[5] = 0; r[6] = 0; r[7] = 0;
    return r;
}

// ---------------------------------------------------------------------
// Kernel 1: per-row L2 norm over concat(a,b); write fp4-e2m1 nibbles of
// (x_norm * 64). Optionally also write bf16 normalized rows (xb) for
// the loss gather. Zeroes best[row].
// ---------------------------------------------------------------------
__global__ __launch_bounds__(256) void normalize_kernel(
    const float* __restrict__ a, const float* __restrict__ b,
    unsigned char* __restrict__ xq, float* __restrict__ invn,
    unsigned long long* __restrict__ best,
    unsigned* __restrict__ xb) {           // nullable
    int wave = threadIdx.x >> 6;
    int lane = threadIdx.x & 63;
    int row  = blockIdx.x * 4 + wave;

    const float2* pa = (const float2*)(a + (size_t)row * DHALF);  // 192 pairs
    const float2* pb = (const float2*)(b + (size_t)row * DHALF);

    float2 va[3], vb[3];
    float s = 0.0f;
#pragma unroll
    for (int it = 0; it < 3; ++it) {
        va[it] = pa[lane + 64 * it];
        s += va[it].x * va[it].x + va[it].y * va[it].y;
    }
#pragma unroll
    for (int it = 0; it < 3; ++it) {
        vb[it] = pb[lane + 64 * it];
        s += vb[it].x * vb[it].x + vb[it].y * vb[it].y;
    }
#pragma unroll
    for (int d = 1; d < 64; d <<= 1) s += __shfl_xor(s, d, 64);

    float inv = 1.0f / fmaxf(sqrtf(s), EPSF);
    if (lane == 0) { invn[row] = inv; best[row] = 0ull; }
    float qs = inv * QSCALE;

    unsigned char* px = xq + (size_t)row * ROWB;
#pragma unroll
    for (int it = 0; it < 3; ++it)
        px[lane + 64 * it] =
            (unsigned char)(enc_fp4(va[it].x * qs) | (enc_fp4(va[it].y * qs) << 4));
#pragma unroll
    for (int it = 0; it < 3; ++it)
        px[192 + lane + 64 * it] =
            (unsigned char)(enc_fp4(vb[it].x * qs) | (enc_fp4(vb[it].y * qs) << 4));

    if (xb) {   // uniform branch
        unsigned* pw = xb + (size_t)row * (DFULL / 2);   // 384 packed pairs
#pragma unroll
        for (int it = 0; it < 3; ++it)
            pw[lane + 64 * it] =
                f2bf(va[it].x * inv) | (f2bf(va[it].y * inv) << 16);
#pragma unroll
        for (int it = 0; it < 3; ++it)
            pw[192 + lane + 64 * it] =
                f2bf(vb[it].x * inv) | (f2bf(vb[it].y * inv) << 16);
    }
}

// ---------------------------------------------------------------------
// Kernel 2: scaled dots via MX-fp4 16x16x128 MFMA, 128x128 tile, BK=128
// elems = 64 B/row, upper-triangle blocks (symmetry). R13: 3-buffer LDS
// pipeline staged 2 K-steps ahead, counted s_waitcnt vmcnt(4) barriers
// (T3/T4), WITH the register-clean to8() operand pattern (R12's scratch
// spill reverted).
// ---------------------------------------------------------------------
__global__ __launch_bounds__(256, 3) void argmax_kernel(
    const unsigned char* __restrict__ xq,
    unsigned long long* __restrict__ best) {
    __shared__ unsigned char As[3][128 * 64];
    __shared__ unsigned char Bs[3][128 * 64];

    // decode upper-triangle pair: k -> (rb <= cb)
    int k = blockIdx.x;
    int i = (int)((sqrtf(8.0f * (float)k + 1.0f) - 1.0f) * 0.5f);
    while ((i + 1) * (i + 2) / 2 <= k) ++i;
    while (i * (i + 1) / 2 > k) --i;
    int cb = i;
    int rb = k - i * (i + 1) / 2;   // rb <= cb
    int r0 = rb * 128, c0 = cb * 128;

    int tid  = threadIdx.x;
    int wave = tid >> 6, lane = tid & 63;
    int wr = wave >> 1, wc = wave & 1;
    int quad = lane >> 4, l15 = lane & 15;

    f32x4 acc[4][4] = {};
    const int SC = 0x7f7f7f7f;      // e8m0 scales = 1.0 in every byte

    // staging pointers: 2 rounds x 256 threads cover 512 granules/tile
    const unsigned char* gA[2];
    const unsigned char* gB[2];
    int lofs[2];
#pragma unroll
    for (int r2 = 0; r2 < 2; ++r2) {
        int idx = r2 * 256 + tid;          // 0..511
        int r   = idx >> 2;                // 0..127
        int s   = idx & 3;                 // dst slot
        int g   = s ^ ((r ^ (r >> 2)) & 3);   // swizzled source granule
        gA[r2] = xq + (size_t)(r0 + r) * ROWB + (g << 4);
        gB[r2] = xq + (size_t)(c0 + r) * ROWB + (g << 4);
        lofs[r2] = idx * 16;
    }

    // fragment LDS offsets (loop-invariant)
    int s0 = ((quad ^ ((l15 ^ (l15 >> 2)) & 3)) << 4);
    int aof[4], bof[4];
#pragma unroll
    for (int t = 0; t < 4; ++t) {
        aof[t] = (wr * 64 + t * 16 + l15) * 64 + s0;
        bof[t] = (wc * 64 + t * 16 + l15) * 64 + s0;
    }

    auto stage = [&](int k0b, int buf) {
        async_copy16(gA[0] + k0b, &As[buf][lofs[0]]);
        async_copy16(gA[1] + k0b, &As[buf][lofs[1]]);
        async_copy16(gB[0] + k0b, &Bs[buf][lofs[0]]);
        async_copy16(gB[1] + k0b, &Bs[buf][lofs[1]]);
    };
    auto compute = [&](int buf) {
        const unsigned char* Ab = As[buf];
        const unsigned char* Bb = Bs[buf];
        int8v bfr[4];
#pragma unroll
        for (int t = 0; t < 4; ++t)
            bfr[t] = to8(*(const int4v*)(&Bb[bof[t]]));
#pragma unroll
        for (int ti = 0; ti < 4; ++ti) {
            int8v a8 = to8(*(const int4v*)(&Ab[aof[ti]]));
#pragma unroll
            for (int tj = 0; tj < 4; ++tj)
                acc[ti][tj] = __builtin_amdgcn_mfma_scale_f32_16x16x128_f8f6f4(
                    a8, bfr[tj], acc[ti][tj], 4, 4, 0, SC, 0, SC);
        }
    };

    // ---- 6 K-steps, 3 buffers, staged 2 ahead, counted vmcnt ----
    // each stage = 4 copies/thread; vmcnt(4) at a barrier => the buffer
    // about to be computed has landed, the newest stage stays in flight.
    stage(0, 0);
    stage(64, 1);
    PIPE_SYNC(4);            // buf0 landed; buf1 in flight

    stage(128, 2); compute(0);
    PIPE_SYNC(4);            // buf1 landed; buf2 in flight
    stage(192, 0); compute(1);
    PIPE_SYNC(4);            // buf2 landed; buf0(k192) in flight
    stage(256, 1); compute(2);
    PIPE_SYNC(4);            // buf0 landed; buf1(k256) in flight
    stage(320, 2); compute(0);
    PIPE_SYNC(4);            // buf1 landed; buf2(k320) in flight
    compute(1);
    PIPE_SYNC(0);            // drain: buf2 landed
    compute(2);              // last tile; epilogue is register-only

    int rbase = r0 + wr * 64, cbase = c0 + wc * 64;

    // Diagonal mask: only possible in diagonal blocks, and only in waves
    // with wr==wc. Hoisted here so the hot epilogue below is mask-free.
    if (rb == cb && wr == wc) {
#pragma unroll
        for (int ti = 0; ti < 4; ++ti)
#pragma unroll
            for (int reg = 0; reg < 4; ++reg)
                if (l15 == quad * 4 + reg)
                    acc[ti][ti][reg] = -1.0e30f;
    }

    // Row-direction: float key = (bits & ~63) | (tj<<4 | l15); fmax + DPP
    // reduce; monotone transform applied once to the 16-lane winner.
#pragma unroll
    for (int ti = 0; ti < 4; ++ti) {
#pragma unroll
        for (int reg = 0; reg < 4; ++reg) {
            float f0 = kf(acc[ti][0][reg], (unsigned)((0 << 4) | l15));
            float f1 = kf(acc[ti][1][reg], (unsigned)((1 << 4) | l15));
            float f2 = kf(acc[ti][2][reg], (unsigned)((2 << 4) | l15));
            float f3 = kf(acc[ti][3][reg], (unsigned)((3 << 4) | l15));
            float fk = fmaxf(fmaxf(f0, f1), fmaxf(f2, f3));
            fk = fmax_ror<0x121>(fk);   // ror 1
            fk = fmax_ror<0x122>(fk);   // ror 2
            fk = fmax_ror<0x124>(fk);   // ror 4
            fk = fmax_ror<0x128>(fk);   // ror 8
            if (l15 == 0) {
                unsigned kb = __float_as_uint(fk);
                int grow = rbase + ti * 16 + quad * 4 + reg;
                int col  = cbase + (int)(((kb >> 4) & 3u) * 16u + (kb & 15u));
                unsigned long long gk =
                    ((unsigned long long)(mono_bits(kb) & ~63u) << 32) |
                    (unsigned)col;
                atomicMax(&best[grow], gk);
            }
        }
    }

    // Column-direction (off-diagonal blocks): 16 in-lane candidates,
    // then 2 cross-lane maxes; key idx = (ti<<4)|(quad<<2)|reg.
    if (rb != cb) {
#pragma unroll
        for (int tj = 0; tj < 4; ++tj) {
            float fk = kf(acc[0][tj][0], (unsigned)(quad << 2));
#pragma unroll
            for (int ti = 0; ti < 4; ++ti)
#pragma unroll
                for (int reg = 0; reg < 4; ++reg)
                    if (ti | reg)
                        fk = fmaxf(fk, kf(acc[ti][tj][reg],
                                (unsigned)((ti << 4) | (quad << 2) | reg)));
            fk = fmaxf(fk, __shfl_xor(fk, 16, 64));
            fk = fmaxf(fk, __shfl_xor(fk, 32, 64));
            if (quad == 0) {
                unsigned kb = __float_as_uint(fk);
                int grow = rbase + (int)(((kb >> 4) & 3u) * 16u +
                                         ((kb >> 2) & 3u) * 4u + (kb & 3u));
                int gcol = cbase + tj * 16 + l15;
                unsigned long long gk =
                    ((unsigned long long)(mono_bits(kb) & ~63u) << 32) |
                    (unsigned)grow;
                atomicMax(&best[gcol], gk);
            }
        }
    }
}

// ---------------------------------------------------------------------
// Kernel 3a: loss from bf16 normalized rows (50 MB vs 100 MB fp32 path)
// ---------------------------------------------------------------------
__global__ __launch_bounds__(256) void loss_bf16_kernel(
    const unsigned* __restrict__ xb,
    const unsigned long long* __restrict__ best,
    float* __restrict__ terms) {
    int wave = threadIdx.x >> 6;
    int lane = threadIdx.x & 63;
    int row  = blockIdx.x * 4 + wave;

    int j = (int)(best[row] & 0xffffffffull);
    const uint2* pi = (const uint2*)(xb + (size_t)row * (DFULL / 2));
    const uint2* pj = (const uint2*)(xb + (size_t)j   * (DFULL / 2));

    float s = 0.0f;
#pragma unroll
    for (int it = 0; it < 3; ++it) {
        int kk = lane + 64 * it;
        uint2 wi = pi[kk], wj = pj[kk];
        float d0 = bf_lo(wi.x) - bf_lo(wj.x) + EPSF;
        float d1 = bf_hi(wi.x) - bf_hi(wj.x) + EPSF;
        float d2 = bf_lo(wi.y) - bf_lo(wj.y) + EPSF;
        float d3 = bf_hi(wi.y) - bf_hi(wj.y) + EPSF;
        s += d0 * d0 + d1 * d1 + d2 * d2 + d3 * d3;
    }
#pragma unroll
    for (int d = 1; d < 64; d <<= 1) s += __shfl_xor(s, d, 64);

    if (lane == 0) terms[row] = logf(sqrtf(s) + EPSF);
}

// ---------------------------------------------------------------------
// Kernel 3b: fallback — loss from fp32 originals (if ws too small)
// ---------------------------------------------------------------------
__global__ __launch_bounds__(256) void loss_kernel(
    const float* __restrict__ a, const float* __restrict__ b,
    const float* __restrict__ invn,
    const unsigned long long* __restrict__ best,
    float* __restrict__ terms) {
    int wave = threadIdx.x >> 6;
    int lane = threadIdx.x & 63;
    int row  = blockIdx.x * 4 + wave;

    int j = (int)(best[row] & 0xffffffffull);
    float ii = invn[row], ij = invn[j];

    const float2* pai = (const float2*)(a + (size_t)row * DHALF);
    const float2* pbi = (const float2*)(b + (size_t)row * DHALF);
    const float2* paj = (const float2*)(a + (size_t)j * DHALF);
    const float2* pbj = (const float2*)(b + (size_t)j * DHALF);

    float s = 0.0f;
#pragma unroll
    for (int it = 0; it < 3; ++it) {
        int kk = lane + 64 * it;
        float2 di = pai[kk], dj = paj[kk];
        float dx = di.x * ii - dj.x * ij + EPSF;
        float dy = di.y * ii - dj.y * ij + EPSF;
        s += dx * dx + dy * dy;
    }
#pragma unroll
    for (int it = 0; it < 3; ++it) {
        int kk = lane + 64 * it;
        float2 di = pbi[kk], dj = pbj[kk];
        float dx = di.x * ii - dj.x * ij + EPSF;
        float dy = di.y * ii - dj.y * ij + EPSF;
        s += dx * dx + dy * dy;
    }
#pragma unroll
    for (int d = 1; d < 64; d <<= 1) s += __shfl_xor(s, d, 64);

    if (lane == 0) terms[row] = logf(sqrtf(s) + EPSF);
}

// ---------------------------------------------------------------------
// Kernel 4: single-block tree reduction of terms -> out[0] = -mean
// ---------------------------------------------------------------------
__global__ __launch_bounds__(1024) void reduce_kernel(
    const float* __restrict__ terms, float* __restrict__ out) {
    __shared__ float partial[16];
    int tid = threadIdx.x;
    float s = 0.0f;
#pragma unroll
    for (int it = 0; it < NROWS / 1024; ++it) s += terms[tid + 1024 * it];
#pragma unroll
    for (int d = 1; d < 64; d <<= 1) s += __shfl_xor(s, d, 64);
    if ((tid & 63) == 0) partial[tid >> 6] = s;
    __syncthreads();
    if (tid < 16) {
        s = partial[tid];
#pragma unroll
        for (int d = 1; d < 16; d <<= 1) s += __shfl_xor(s, d, 16);
        if (tid == 0) out[0] = -s * (1.0f / (float)NROWS);
    }
}

// ---------------------------------------------------------------------
extern "C" void kernel_launch(void* const* d_in, const int* in_sizes, int n_in,
                              void* d_out, int out_size, void* d_ws, size_t ws_size,
                              hipStream_t stream) {
    const float* a = (const float*)d_in[0];
    const float* b = (const float*)d_in[1];
    float* out = (float*)d_out;

    char* ws = (char*)d_ws;
    unsigned char* xq = (unsigned char*)ws;                                    // 6291456 B
    unsigned long long* best = (unsigned long long*)(ws + 6291456);            // 131072 B
    float* invn  = (float*)(ws + 6291456 + 131072);                            // 65536 B
    float* terms = (float*)(ws + 6291456 + 131072 + 65536);                    // 65536 B
    unsigned* xb = (unsigned*)(ws + 6291456 + 131072 + 65536 + 65536);         // 25165824 B
    const size_t need_xb = 6291456ull + 131072 + 65536 + 65536 + 25165824;
    const bool use_xb = ws_size >= need_xb;   // constant across calls

    const int NTILE = NROWS / 128;                     // 128
    const int NBLK  = NTILE * (NTILE + 1) / 2;         // 8256

    normalize_kernel<<<NROWS / 4, 256, 0, stream>>>(
        a, b, xq, invn, best, use_xb ? xb : (unsigned*)nullptr);
    argmax_kernel<<<NBLK, 256, 0, stream>>>(xq, best);
    if (use_xb)
        loss_bf16_kernel<<<NROWS / 4, 256, 0, stream>>>(xb, best, terms);
    else
        loss_kernel<<<NROWS / 4, 256, 0, stream>>>(a, b, invn, best, terms);
    reduce_kernel<<<1, 1024, 0, stream>>>(terms, out);
}

// Round 4
// 227.247 us; speedup vs baseline: 1.7291x; 1.7253x over previous
//
#include <hip/hip_runtime.h>
#include <hip/hip_bf16.h>
#include <stdint.h>
#include <math.h>

#define NROWS 16384
#define DHALF 384
#define DFULL 768
#define ROWB  384      // bytes per fp4 row: 768 elems * 4 bit
#define EPSF  1e-8f
#define QSCALE 64.0f   // N(0,0.036)*64 -> N(0,2.3): centered in e2m1 range +-6

typedef __attribute__((ext_vector_type(4)))  float f32x4;
typedef __attribute__((ext_vector_type(4)))  int   int4v;
typedef __attribute__((ext_vector_type(8)))  int   int8v;

// ---- async global->LDS, 16B per lane (wave-uniform base + lane*16) ----
__device__ __forceinline__ void async_copy16(const void* gptr, void* lptr) {
    __builtin_amdgcn_global_load_lds(
        (const __attribute__((address_space(1))) unsigned int*)gptr,
        (__attribute__((address_space(3))) unsigned int*)lptr,
        16, 0, 0);
}

// counted-vmcnt barrier (T4): wait until <=N vector-mem ops outstanding,
// then barrier. N=4 keeps the newest stage's 4 global_load_lds in flight
// ACROSS the barrier. sched_barrier(0) pins backend scheduling (rule #18).
// NOTE (R12/R13 lesson): the "memory" clobber is safe ONLY if no live
// value sits in an addressable alloca — hence the named-SSA acc below.
#define PIPE_SYNC(N)                                            \
    do {                                                        \
        asm volatile("s_waitcnt vmcnt(" #N ")" ::: "memory");   \
        __builtin_amdgcn_s_barrier();                           \
        __builtin_amdgcn_sched_barrier(0);                      \
    } while (0)

// monotone u32 from raw float bits (order-preserving for all finite floats)
__device__ __forceinline__ unsigned mono_bits(unsigned u) {
    return u ^ ((unsigned)(((int)u) >> 31) | 0x80000000u);
}

// float key: clear low 6 mantissa bits, embed 6-bit index. IEEE compare
// order == value order (perturbation <= 2^-18 relative, harmless after
// fp4 quantization); winner carries its index.
__device__ __forceinline__ float kf(float v, unsigned idx) {
    return __uint_as_float((__float_as_uint(v) & ~63u) | idx);
}

// float max with a DPP row_ror'd copy (16-lane row, pure VALU)
template <int CTRL>
__device__ __forceinline__ float fmax_ror(float v) {
    float t = __int_as_float(__builtin_amdgcn_update_dpp(
        0, __float_as_int(v), CTRL, 0xF, 0xF, false));
    return fmaxf(v, t);
}

// fp4 e2m1 encode, round-to-nearest: values {0,.5,1,1.5,2,3,4,6} (+sign)
__device__ __forceinline__ unsigned enc_fp4(float v) {
    float a = fabsf(v);
    unsigned c = (unsigned)(a >= 0.25f) + (a >= 0.75f) + (a >= 1.25f) +
                 (a >= 1.75f) + (a >= 2.5f) + (a >= 3.5f) + (a >= 5.0f);
    return c | (v < 0.0f ? 8u : 0u);
}

// fp32 -> bf16 bits, round-to-nearest-even (no NaN inputs here)
__device__ __forceinline__ unsigned f2bf(float f) {
    unsigned u = __float_as_uint(f);
    return (u + (((u >> 16) & 1u) + 0x7fffu)) >> 16;
}
__device__ __forceinline__ float bf_lo(unsigned w) {   // low bf16 of packed pair
    return __uint_as_float(w << 16);
}
__device__ __forceinline__ float bf_hi(unsigned w) {   // high bf16
    return __uint_as_float(w & 0xffff0000u);
}

// fp4 operand: HW reads only v[0:3] of the 8-reg tuple (cbsz/blgp=4).
// High half is compile-time zero; by-value return, SSA-friendly.
__device__ __forceinline__ int8v to8(int4v q) {
    int8v r;
    r[0] = q[0]; r[1] = q[1]; r[2] = q[2]; r[3] = q[3];
    r[4] = 0; r[5] = 0; r[6] = 0; r[7] = 0;
    return r;
}

// ---------------------------------------------------------------------
// Kernel 1: per-row L2 norm over concat(a,b); write fp4-e2m1 nibbles of
// (x_norm * 64). Optionally also write bf16 normalized rows (xb) for
// the loss gather. Zeroes best[row].
// ---------------------------------------------------------------------
__global__ __launch_bounds__(256) void normalize_kernel(
    const float* __restrict__ a, const float* __restrict__ b,
    unsigned char* __restrict__ xq, float* __restrict__ invn,
    unsigned long long* __restrict__ best,
    unsigned* __restrict__ xb) {           // nullable
    int wave = threadIdx.x >> 6;
    int lane = threadIdx.x & 63;
    int row  = blockIdx.x * 4 + wave;

    const float2* pa = (const float2*)(a + (size_t)row * DHALF);  // 192 pairs
    const float2* pb = (const float2*)(b + (size_t)row * DHALF);

    float2 va[3], vb[3];
    float s = 0.0f;
#pragma unroll
    for (int it = 0; it < 3; ++it) {
        va[it] = pa[lane + 64 * it];
        s += va[it].x * va[it].x + va[it].y * va[it].y;
    }
#pragma unroll
    for (int it = 0; it < 3; ++it) {
        vb[it] = pb[lane + 64 * it];
        s += vb[it].x * vb[it].x + vb[it].y * vb[it].y;
    }
#pragma unroll
    for (int d = 1; d < 64; d <<= 1) s += __shfl_xor(s, d, 64);

    float inv = 1.0f / fmaxf(sqrtf(s), EPSF);
    if (lane == 0) { invn[row] = inv; best[row] = 0ull; }
    float qs = inv * QSCALE;

    unsigned char* px = xq + (size_t)row * ROWB;
#pragma unroll
    for (int it = 0; it < 3; ++it)
        px[lane + 64 * it] =
            (unsigned char)(enc_fp4(va[it].x * qs) | (enc_fp4(va[it].y * qs) << 4));
#pragma unroll
    for (int it = 0; it < 3; ++it)
        px[192 + lane + 64 * it] =
            (unsigned char)(enc_fp4(vb[it].x * qs) | (enc_fp4(vb[it].y * qs) << 4));

    if (xb) {   // uniform branch
        unsigned* pw = xb + (size_t)row * (DFULL / 2);   // 384 packed pairs
#pragma unroll
        for (int it = 0; it < 3; ++it)
            pw[lane + 64 * it] =
                f2bf(va[it].x * inv) | (f2bf(va[it].y * inv) << 16);
#pragma unroll
        for (int it = 0; it < 3; ++it)
            pw[192 + lane + 64 * it] =
                f2bf(vb[it].x * inv) | (f2bf(vb[it].y * inv) << 16);
    }
}

// ---------------------------------------------------------------------
// Kernel 2: scaled dots via MX-fp4 16x16x128 MFMA, 128x128 tile,
// upper-triangle blocks. R14: 3-buffer LDS pipeline staged 2 K-steps
// ahead with counted vmcnt(4) barriers, written as straight-line macro
// code with 16 NAMED f32x4 accumulators — no lambdas, no addressable
// locals, so the asm "memory" clobber cannot force a scratch spill
// (R12/R13: escaped acc alloca -> 1.1 GB scratch traffic).
// ---------------------------------------------------------------------
__global__ __launch_bounds__(256, 3) void argmax_kernel(
    const unsigned char* __restrict__ xq,
    unsigned long long* __restrict__ best) {
    __shared__ unsigned char As[3][128 * 64];
    __shared__ unsigned char Bs[3][128 * 64];

    // decode upper-triangle pair: k -> (rb <= cb)
    int k = blockIdx.x;
    int i = (int)((sqrtf(8.0f * (float)k + 1.0f) - 1.0f) * 0.5f);
    while ((i + 1) * (i + 2) / 2 <= k) ++i;
    while (i * (i + 1) / 2 > k) --i;
    int cb = i;
    int rb = k - i * (i + 1) / 2;   // rb <= cb
    int r0 = rb * 128, c0 = cb * 128;

    int tid  = threadIdx.x;
    int wave = tid >> 6, lane = tid & 63;
    int wr = wave >> 1, wc = wave & 1;
    int quad = lane >> 4, l15 = lane & 15;

    const int SC = 0x7f7f7f7f;      // e8m0 scales = 1.0 in every byte

    // 16 named accumulators — pure SSA, address can never be taken.
    f32x4 a00 = {}, a01 = {}, a02 = {}, a03 = {};
    f32x4 a10 = {}, a11 = {}, a12 = {}, a13 = {};
    f32x4 a20 = {}, a21 = {}, a22 = {}, a23 = {};
    f32x4 a30 = {}, a31 = {}, a32 = {}, a33 = {};

    // staging pointers: 2 rounds x 256 threads cover 512 granules/tile
    const unsigned char* gA[2];
    const unsigned char* gB[2];
    int lofs[2];
#pragma unroll
    for (int r2 = 0; r2 < 2; ++r2) {
        int idx = r2 * 256 + tid;          // 0..511
        int r   = idx >> 2;                // 0..127
        int s   = idx & 3;                 // dst slot
        int g   = s ^ ((r ^ (r >> 2)) & 3);   // swizzled source granule
        gA[r2] = xq + (size_t)(r0 + r) * ROWB + (g << 4);
        gB[r2] = xq + (size_t)(c0 + r) * ROWB + (g << 4);
        lofs[r2] = idx * 16;
    }

    // fragment LDS offsets (loop-invariant, literal-indexed only)
    int s0 = ((quad ^ ((l15 ^ (l15 >> 2)) & 3)) << 4);
    int aof[4], bof[4];
#pragma unroll
    for (int t = 0; t < 4; ++t) {
        aof[t] = (wr * 64 + t * 16 + l15) * 64 + s0;
        bof[t] = (wc * 64 + t * 16 + l15) * 64 + s0;
    }

#define STAGE(k0b, buf) do {                                \
    async_copy16(gA[0] + (k0b), &As[buf][lofs[0]]);         \
    async_copy16(gA[1] + (k0b), &As[buf][lofs[1]]);         \
    async_copy16(gB[0] + (k0b), &Bs[buf][lofs[0]]);         \
    async_copy16(gB[1] + (k0b), &Bs[buf][lofs[1]]);         \
} while (0)

#define MFMA1(d, x, b)                                                  \
    d = __builtin_amdgcn_mfma_scale_f32_16x16x128_f8f6f4(               \
            x, b, d, 4, 4, 0, SC, 0, SC)

#define COMPUTE(buf) do {                                               \
    const unsigned char* Ab_ = As[buf];                                 \
    const unsigned char* Bb_ = Bs[buf];                                 \
    int8v b0_ = to8(*(const int4v*)(&Bb_[bof[0]]));                     \
    int8v b1_ = to8(*(const int4v*)(&Bb_[bof[1]]));                     \
    int8v b2_ = to8(*(const int4v*)(&Bb_[bof[2]]));                     \
    int8v b3_ = to8(*(const int4v*)(&Bb_[bof[3]]));                     \
    {   int8v x_ = to8(*(const int4v*)(&Ab_[aof[0]]));                  \
        MFMA1(a00, x_, b0_); MFMA1(a01, x_, b1_);                       \
        MFMA1(a02, x_, b2_); MFMA1(a03, x_, b3_); }                     \
    {   int8v x_ = to8(*(const int4v*)(&Ab_[aof[1]]));                  \
        MFMA1(a10, x_, b0_); MFMA1(a11, x_, b1_);                       \
        MFMA1(a12, x_, b2_); MFMA1(a13, x_, b3_); }                     \
    {   int8v x_ = to8(*(const int4v*)(&Ab_[aof[2]]));                  \
        MFMA1(a20, x_, b0_); MFMA1(a21, x_, b1_);                       \
        MFMA1(a22, x_, b2_); MFMA1(a23, x_, b3_); }                     \
    {   int8v x_ = to8(*(const int4v*)(&Ab_[aof[3]]));                  \
        MFMA1(a30, x_, b0_); MFMA1(a31, x_, b1_);                       \
        MFMA1(a32, x_, b2_); MFMA1(a33, x_, b3_); }                     \
} while (0)

    // ---- 6 K-steps, 3 buffers, staged 2 ahead, counted vmcnt ----
    // each STAGE = 4 copies/wave; vmcnt(4) at a barrier => the buffer
    // about to be computed has landed, the newest stage stays in flight.
    STAGE(0, 0);
    STAGE(64, 1);
    PIPE_SYNC(4);                    // buf0 landed; buf1 in flight

    STAGE(128, 2); COMPUTE(0);
    PIPE_SYNC(4);                    // buf1 landed; buf2 in flight
    STAGE(192, 0); COMPUTE(1);
    PIPE_SYNC(4);                    // buf2 landed; buf0' in flight
    STAGE(256, 1); COMPUTE(2);
    PIPE_SYNC(4);                    // buf0' landed; buf1' in flight
    STAGE(320, 2); COMPUTE(0);
    PIPE_SYNC(4);                    // buf1' landed; buf2' in flight
    COMPUTE(1);
    PIPE_SYNC(0);                    // drain: buf2' landed
    COMPUTE(2);                      // last tile; epilogue register-only

    int rbase = r0 + wr * 64, cbase = c0 + wc * 64;

    // Diagonal mask: only in diagonal blocks, only waves with wr==wc.
    if (rb == cb && wr == wc) {
#pragma unroll
        for (int reg = 0; reg < 4; ++reg)
            if (l15 == quad * 4 + reg) {
                a00[reg] = -1.0e30f; a11[reg] = -1.0e30f;
                a22[reg] = -1.0e30f; a33[reg] = -1.0e30f;
            }
    }

    // Row-direction: float key = (bits & ~63)|(tj<<4|l15); fmax + DPP
    // tree; monotone transform applied once to the 16-lane winner.
#define ROWRED(ti, T0, T1, T2, T3) do {                                     \
    _Pragma("unroll")                                                       \
    for (int reg = 0; reg < 4; ++reg) {                                     \
        float f0 = kf(T0[reg], (unsigned)((0 << 4) | l15));                 \
        float f1 = kf(T1[reg], (unsigned)((1 << 4) | l15));                 \
        float f2 = kf(T2[reg], (unsigned)((2 << 4) | l15));                 \
        float f3 = kf(T3[reg], (unsigned)((3 << 4) | l15));                 \
        float fk = fmaxf(fmaxf(f0, f1), fmaxf(f2, f3));                     \
        fk = fmax_ror<0x121>(fk);                                           \
        fk = fmax_ror<0x122>(fk);                                           \
        fk = fmax_ror<0x124>(fk);                                           \
        fk = fmax_ror<0x128>(fk);                                           \
        if (l15 == 0) {                                                     \
            unsigned kb = __float_as_uint(fk);                              \
            int grow = rbase + (ti) * 16 + quad * 4 + reg;                  \
            int col  = cbase + (int)(((kb >> 4) & 3u) * 16u + (kb & 15u));  \
            unsigned long long gk =                                         \
                ((unsigned long long)(mono_bits(kb) & ~63u) << 32) |        \
                (unsigned)col;                                              \
            atomicMax(&best[grow], gk);                                     \
        }                                                                   \
    }                                                                       \
} while (0)

    ROWRED(0, a00, a01, a02, a03);
    ROWRED(1, a10, a11, a12, a13);
    ROWRED(2, a20, a21, a22, a23);
    ROWRED(3, a30, a31, a32, a33);

    // Column-direction (off-diagonal blocks): 16 in-lane candidates,
    // then 2 cross-lane maxes; key idx = (ti<<4)|(quad<<2)|reg.
#define COLRED(tj, T0, T1, T2, T3) do {                                       \
    float fk = kf(T0[0], (unsigned)(quad << 2));                              \
    _Pragma("unroll")                                                         \
    for (int reg = 1; reg < 4; ++reg)                                         \
        fk = fmaxf(fk, kf(T0[reg], (unsigned)((quad << 2) | reg)));           \
    _Pragma("unroll")                                                         \
    for (int reg = 0; reg < 4; ++reg)                                         \
        fk = fmaxf(fk, kf(T1[reg], (unsigned)((1 << 4) | (quad << 2) | reg)));\
    _Pragma("unroll")                                                         \
    for (int reg = 0; reg < 4; ++reg)                                         \
        fk = fmaxf(fk, kf(T2[reg], (unsigned)((2 << 4) | (quad << 2) | reg)));\
    _Pragma("unroll")                                                         \
    for (int reg = 0; reg < 4; ++reg)                                         \
        fk = fmaxf(fk, kf(T3[reg], (unsigned)((3 << 4) | (quad << 2) | reg)));\
    fk = fmaxf(fk, __shfl_xor(fk, 16, 64));                                   \
    fk = fmaxf(fk, __shfl_xor(fk, 32, 64));                                   \
    if (quad == 0) {                                                          \
        unsigned kb = __float_as_uint(fk);                                    \
        int grow = rbase + (int)(((kb >> 4) & 3u) * 16u +                     \
                                 ((kb >> 2) & 3u) * 4u + (kb & 3u));          \
        int gcol = cbase + (tj) * 16 + l15;                                   \
        unsigned long long gk =                                               \
            ((unsigned long long)(mono_bits(kb) & ~63u) << 32) |              \
            (unsigned)grow;                                                   \
        atomicMax(&best[gcol], gk);                                           \
    }                                                                         \
} while (0)

    if (rb != cb) {
        COLRED(0, a00, a10, a20, a30);
        COLRED(1, a01, a11, a21, a31);
        COLRED(2, a02, a12, a22, a32);
        COLRED(3, a03, a13, a23, a33);
    }

#undef STAGE
#undef MFMA1
#undef COMPUTE
#undef ROWRED
#undef COLRED
}

// ---------------------------------------------------------------------
// Kernel 3a: loss from bf16 normalized rows (50 MB vs 100 MB fp32 path)
// ---------------------------------------------------------------------
__global__ __launch_bounds__(256) void loss_bf16_kernel(
    const unsigned* __restrict__ xb,
    const unsigned long long* __restrict__ best,
    float* __restrict__ terms) {
    int wave = threadIdx.x >> 6;
    int lane = threadIdx.x & 63;
    int row  = blockIdx.x * 4 + wave;

    int j = (int)(best[row] & 0xffffffffull);
    const uint2* pi = (const uint2*)(xb + (size_t)row * (DFULL / 2));
    const uint2* pj = (const uint2*)(xb + (size_t)j   * (DFULL / 2));

    float s = 0.0f;
#pragma unroll
    for (int it = 0; it < 3; ++it) {
        int kk = lane + 64 * it;
        uint2 wi = pi[kk], wj = pj[kk];
        float d0 = bf_lo(wi.x) - bf_lo(wj.x) + EPSF;
        float d1 = bf_hi(wi.x) - bf_hi(wj.x) + EPSF;
        float d2 = bf_lo(wi.y) - bf_lo(wj.y) + EPSF;
        float d3 = bf_hi(wi.y) - bf_hi(wj.y) + EPSF;
        s += d0 * d0 + d1 * d1 + d2 * d2 + d3 * d3;
    }
#pragma unroll
    for (int d = 1; d < 64; d <<= 1) s += __shfl_xor(s, d, 64);

    if (lane == 0) terms[row] = logf(sqrtf(s) + EPSF);
}

// ---------------------------------------------------------------------
// Kernel 3b: fallback — loss from fp32 originals (if ws too small)
// ---------------------------------------------------------------------
__global__ __launch_bounds__(256) void loss_kernel(
    const float* __restrict__ a, const float* __restrict__ b,
    const float* __restrict__ invn,
    const unsigned long long* __restrict__ best,
    float* __restrict__ terms) {
    int wave = threadIdx.x >> 6;
    int lane = threadIdx.x & 63;
    int row  = blockIdx.x * 4 + wave;

    int j = (int)(best[row] & 0xffffffffull);
    float ii = invn[row], ij = invn[j];

    const float2* pai = (const float2*)(a + (size_t)row * DHALF);
    const float2* pbi = (const float2*)(b + (size_t)row * DHALF);
    const float2* paj = (const float2*)(a + (size_t)j * DHALF);
    const float2* pbj = (const float2*)(b + (size_t)j * DHALF);

    float s = 0.0f;
#pragma unroll
    for (int it = 0; it < 3; ++it) {
        int kk = lane + 64 * it;
        float2 di = pai[kk], dj = paj[kk];
        float dx = di.x * ii - dj.x * ij + EPSF;
        float dy = di.y * ii - dj.y * ij + EPSF;
        s += dx * dx + dy * dy;
    }
#pragma unroll
    for (int it = 0; it < 3; ++it) {
        int kk = lane + 64 * it;
        float2 di = pbi[kk], dj = pbj[kk];
        float dx = di.x * ii - dj.x * ij + EPSF;
        float dy = di.y * ii - dj.y * ij + EPSF;
        s += dx * dx + dy * dy;
    }
#pragma unroll
    for (int d = 1; d < 64; d <<= 1) s += __shfl_xor(s, d, 64);

    if (lane == 0) terms[row] = logf(sqrtf(s) + EPSF);
}

// ---------------------------------------------------------------------
// Kernel 4: single-block tree reduction of terms -> out[0] = -mean
// ---------------------------------------------------------------------
__global__ __launch_bounds__(1024) void reduce_kernel(
    const float* __restrict__ terms, float* __restrict__ out) {
    __shared__ float partial[16];
    int tid = threadIdx.x;
    float s = 0.0f;
#pragma unroll
    for (int it = 0; it < NROWS / 1024; ++it) s += terms[tid + 1024 * it];
#pragma unroll
    for (int d = 1; d < 64; d <<= 1) s += __shfl_xor(s, d, 64);
    if ((tid & 63) == 0) partial[tid >> 6] = s;
    __syncthreads();
    if (tid < 16) {
        s = partial[tid];
#pragma unroll
        for (int d = 1; d < 16; d <<= 1) s += __shfl_xor(s, d, 16);
        if (tid == 0) out[0] = -s * (1.0f / (float)NROWS);
    }
}

// ---------------------------------------------------------------------
extern "C" void kernel_launch(void* const* d_in, const int* in_sizes, int n_in,
                              void* d_out, int out_size, void* d_ws, size_t ws_size,
                              hipStream_t stream) {
    const float* a = (const float*)d_in[0];
    const float* b = (const float*)d_in[1];
    float* out = (float*)d_out;

    char* ws = (char*)d_ws;
    unsigned char* xq = (unsigned char*)ws;                                    // 6291456 B
    unsigned long long* best = (unsigned long long*)(ws + 6291456);            // 131072 B
    float* invn  = (float*)(ws + 6291456 + 131072);                            // 65536 B
    float* terms = (float*)(ws + 6291456 + 131072 + 65536);                    // 65536 B
    unsigned* xb = (unsigned*)(ws + 6291456 + 131072 + 65536 + 65536);         // 25165824 B
    const size_t need_xb = 6291456ull + 131072 + 65536 + 65536 + 25165824;
    const bool use_xb = ws_size >= need_xb;   // constant across calls

    const int NTILE = NROWS / 128;                     // 128
    const int NBLK  = NTILE * (NTILE + 1) / 2;         // 8256

    normalize_kernel<<<NROWS / 4, 256, 0, stream>>>(
        a, b, xq, invn, best, use_xb ? xb : (unsigned*)nullptr);
    argmax_kernel<<<NBLK, 256, 0, stream>>>(xq, best);
    if (use_xb)
        loss_bf16_kernel<<<NROWS / 4, 256, 0, stream>>>(xb, best, terms);
    else
        loss_kernel<<<NROWS / 4, 256, 0, stream>>>(a, b, invn, best, terms);
    reduce_kernel<<<1, 1024, 0, stream>>>(terms, out);
}

// Round 5
// 190.033 us; speedup vs baseline: 2.0677x; 1.1958x over previous
//
#include <hip/hip_runtime.h>
#include <hip/hip_bf16.h>
#include <stdint.h>
#include <math.h>

#define NROWS 16384
#define DHALF 384
#define DFULL 768
#define ROWB  384      // bytes per fp4 row: 768 elems * 4 bit
#define EPSF  1e-8f
#define QSCALE 64.0f   // N(0,0.036)*64 -> N(0,2.3): centered in e2m1 range +-6
#define NTILE (NROWS / 128)   // 128 tile-rows/cols

typedef __attribute__((ext_vector_type(4)))  float f32x4;
typedef __attribute__((ext_vector_type(4)))  int   int4v;
typedef __attribute__((ext_vector_type(8)))  int   int8v;

// ---- async global->LDS, 16B per lane (wave-uniform base + lane*16) ----
__device__ __forceinline__ void async_copy16(const void* gptr, void* lptr) {
    __builtin_amdgcn_global_load_lds(
        (const __attribute__((address_space(1))) unsigned int*)gptr,
        (__attribute__((address_space(3))) unsigned int*)lptr,
        16, 0, 0);
}

// monotone u32 from raw float bits (order-preserving for all finite floats)
__device__ __forceinline__ unsigned mono_bits(unsigned u) {
    return u ^ ((unsigned)(((int)u) >> 31) | 0x80000000u);
}

// float key: clear low 6 mantissa bits, embed 6-bit index. IEEE compare
// order == value order (perturbation <= 2^-18 relative, harmless after
// fp4 quantization); winner carries its index.
__device__ __forceinline__ float kf(float v, unsigned idx) {
    return __uint_as_float((__float_as_uint(v) & ~63u) | idx);
}

// float max with a DPP row_ror'd copy (16-lane row, pure VALU)
template <int CTRL>
__device__ __forceinline__ float fmax_ror(float v) {
    float t = __int_as_float(__builtin_amdgcn_update_dpp(
        0, __float_as_int(v), CTRL, 0xF, 0xF, false));
    return fmaxf(v, t);
}

// fp4 e2m1 encode, round-to-nearest: values {0,.5,1,1.5,2,3,4,6} (+sign)
__device__ __forceinline__ unsigned enc_fp4(float v) {
    float a = fabsf(v);
    unsigned c = (unsigned)(a >= 0.25f) + (a >= 0.75f) + (a >= 1.25f) +
                 (a >= 1.75f) + (a >= 2.5f) + (a >= 3.5f) + (a >= 5.0f);
    return c | (v < 0.0f ? 8u : 0u);
}

// fp32 -> bf16 bits, round-to-nearest-even (no NaN inputs here)
__device__ __forceinline__ unsigned f2bf(float f) {
    unsigned u = __float_as_uint(f);
    return (u + (((u >> 16) & 1u) + 0x7fffu)) >> 16;
}
__device__ __forceinline__ float bf_lo(unsigned w) {   // low bf16 of packed pair
    return __uint_as_float(w << 16);
}
__device__ __forceinline__ float bf_hi(unsigned w) {   // high bf16
    return __uint_as_float(w & 0xffff0000u);
}

// fp4 operand: HW reads only v[0:3] of the 8-reg tuple (cbsz/blgp=4).
// High half is compile-time zero — loads are 1x b128.
__device__ __forceinline__ int8v to8(int4v q) {
    int8v r;
    r[0] = q[0]; r[1] = q[1]; r[2] = q[2]; r[3] = q[3];
    r[4] = 0; r[5] = 0; r[6] = 0; r[7] = 0;
    return r;
}

// ---------------------------------------------------------------------
// Kernel 1: per-row L2 norm over concat(a,b); write fp4-e2m1 nibbles of
// (x_norm * 64). Optionally also write bf16 normalized rows (xb) for
// the loss gather. Zeroes best[row] (used by the atomic fallback path).
// ---------------------------------------------------------------------
__global__ __launch_bounds__(256) void normalize_kernel(
    const float* __restrict__ a, const float* __restrict__ b,
    unsigned char* __restrict__ xq, float* __restrict__ invn,
    unsigned long long* __restrict__ best,
    unsigned* __restrict__ xb) {           // nullable
    int wave = threadIdx.x >> 6;
    int lane = threadIdx.x & 63;
    int row  = blockIdx.x * 4 + wave;

    const float2* pa = (const float2*)(a + (size_t)row * DHALF);  // 192 pairs
    const float2* pb = (const float2*)(b + (size_t)row * DHALF);

    float2 va[3], vb[3];
    float s = 0.0f;
#pragma unroll
    for (int it = 0; it < 3; ++it) {
        va[it] = pa[lane + 64 * it];
        s += va[it].x * va[it].x + va[it].y * va[it].y;
    }
#pragma unroll
    for (int it = 0; it < 3; ++it) {
        vb[it] = pb[lane + 64 * it];
        s += vb[it].x * vb[it].x + vb[it].y * vb[it].y;
    }
#pragma unroll
    for (int d = 1; d < 64; d <<= 1) s += __shfl_xor(s, d, 64);

    float inv = 1.0f / fmaxf(sqrtf(s), EPSF);
    if (lane == 0) { invn[row] = inv; best[row] = 0ull; }
    float qs = inv * QSCALE;

    unsigned char* px = xq + (size_t)row * ROWB;
#pragma unroll
    for (int it = 0; it < 3; ++it)
        px[lane + 64 * it] =
            (unsigned char)(enc_fp4(va[it].x * qs) | (enc_fp4(va[it].y * qs) << 4));
#pragma unroll
    for (int it = 0; it < 3; ++it)
        px[192 + lane + 64 * it] =
            (unsigned char)(enc_fp4(vb[it].x * qs) | (enc_fp4(vb[it].y * qs) << 4));

    if (xb) {   // uniform branch
        unsigned* pw = xb + (size_t)row * (DFULL / 2);   // 384 packed pairs
#pragma unroll
        for (int it = 0; it < 3; ++it)
            pw[lane + 64 * it] =
                f2bf(va[it].x * inv) | (f2bf(va[it].y * inv) << 16);
#pragma unroll
        for (int it = 0; it < 3; ++it)
            pw[192 + lane + 64 * it] =
                f2bf(vb[it].x * inv) | (f2bf(vb[it].y * inv) << 16);
    }
}

// ---------------------------------------------------------------------
// Kernel 2: scaled dots via MX-fp4 16x16x128 MFMA, 128x128 tile, BK=128
// elems = 64 B/row, upper-triangle blocks (symmetry). R15: schedule is
// the proven R11 2-buffer __syncthreads pipeline (R12-R14's counted-
// vmcnt 3-buffer variant measured SLOWER: 138 vs 116 us). NEW: the
// epilogue's 4.2M device-scope atomicMax ops (memory-side RMW, 82 MB
// of HBM write, hot 64B lines shared by 8 rows) are replaced by
// race-free plain stores into cand[otile][row] — each (row, other-tile)
// pair has exactly ONE producer: block (R,t) row-reduce for t>=R,
// block (t,R) col-reduce for t<R. best_reduce_kernel finishes the max.
// atomicMax path kept as fallback when ws is too small for cand.
// ---------------------------------------------------------------------
__global__ __launch_bounds__(256, 4) void argmax_kernel(
    const unsigned char* __restrict__ xq,
    unsigned long long* __restrict__ best,
    unsigned long long* __restrict__ cand) {   // nullable -> atomic path
    __shared__ unsigned char As[2][128 * 64];
    __shared__ unsigned char Bs[2][128 * 64];

    // decode upper-triangle pair: k -> (rb <= cb)
    int k = blockIdx.x;
    int i = (int)((sqrtf(8.0f * (float)k + 1.0f) - 1.0f) * 0.5f);
    while ((i + 1) * (i + 2) / 2 <= k) ++i;
    while (i * (i + 1) / 2 > k) --i;
    int cb = i;
    int rb = k - i * (i + 1) / 2;   // rb <= cb
    int r0 = rb * 128, c0 = cb * 128;

    int tid  = threadIdx.x;
    int wave = tid >> 6, lane = tid & 63;
    int wr = wave >> 1, wc = wave & 1;
    int quad = lane >> 4, l15 = lane & 15;

    f32x4 acc[4][4] = {};
    const int SC = 0x7f7f7f7f;      // e8m0 scales = 1.0 in every byte

    // staging pointers: 2 rounds x 256 threads cover 512 granules/tile
    const unsigned char* gA[2];
    const unsigned char* gB[2];
    int lofs[2];
#pragma unroll
    for (int r2 = 0; r2 < 2; ++r2) {
        int idx = r2 * 256 + tid;          // 0..511
        int r   = idx >> 2;                // 0..127
        int s   = idx & 3;                 // dst slot
        int g   = s ^ ((r ^ (r >> 2)) & 3);   // swizzled source granule
        gA[r2] = xq + (size_t)(r0 + r) * ROWB + (g << 4);
        gB[r2] = xq + (size_t)(c0 + r) * ROWB + (g << 4);
        lofs[r2] = idx * 16;
    }

    // fragment LDS offsets (loop-invariant)
    int s0 = ((quad ^ ((l15 ^ (l15 >> 2)) & 3)) << 4);
    int aof[4], bof[4];
#pragma unroll
    for (int t = 0; t < 4; ++t) {
        aof[t] = (wr * 64 + t * 16 + l15) * 64 + s0;
        bof[t] = (wc * 64 + t * 16 + l15) * 64 + s0;
    }

    auto stage = [&](int k0b, int buf) {
        async_copy16(gA[0] + k0b, &As[buf][lofs[0]]);
        async_copy16(gA[1] + k0b, &As[buf][lofs[1]]);
        async_copy16(gB[0] + k0b, &Bs[buf][lofs[0]]);
        async_copy16(gB[1] + k0b, &Bs[buf][lofs[1]]);
    };
    auto compute = [&](int buf) {
        const unsigned char* Ab = As[buf];
        const unsigned char* Bb = Bs[buf];
        int8v bfr[4];
#pragma unroll
        for (int t = 0; t < 4; ++t)
            bfr[t] = to8(*(const int4v*)(&Bb[bof[t]]));
#pragma unroll
        for (int ti = 0; ti < 4; ++ti) {
            int8v a8 = to8(*(const int4v*)(&Ab[aof[ti]]));
#pragma unroll
            for (int tj = 0; tj < 4; ++tj)
                acc[ti][tj] = __builtin_amdgcn_mfma_scale_f32_16x16x128_f8f6f4(
                    a8, bfr[tj], acc[ti][tj], 4, 4, 0, SC, 0, SC);
        }
    };

    stage(0, 0);
    __syncthreads();
    int buf = 0;
#pragma unroll 1
    for (int k0b = 64; k0b < ROWB; k0b += 64) {   // 5 pipelined steps
        stage(k0b, buf ^ 1);
        compute(buf);
        __syncthreads();
        buf ^= 1;
    }
    compute(buf);                // last tile; epilogue is register-only

    int rbase = r0 + wr * 64, cbase = c0 + wc * 64;

    // Diagonal mask: only possible in diagonal blocks, and only in waves
    // with wr==wc. Hoisted here so the hot epilogue below is mask-free.
    if (rb == cb && wr == wc) {
#pragma unroll
        for (int ti = 0; ti < 4; ++ti)
#pragma unroll
            for (int reg = 0; reg < 4; ++reg)
                if (l15 == quad * 4 + reg)
                    acc[ti][ti][reg] = -1.0e30f;
    }

    // Row-direction: float key = (bits & ~63) | (tj<<4 | l15); fmax + DPP
    // reduce; monotone transform applied once to the 16-lane winner.
    // Winner for (grow, tile cb) -> cand[cb][grow], sole producer.
#pragma unroll
    for (int ti = 0; ti < 4; ++ti) {
#pragma unroll
        for (int reg = 0; reg < 4; ++reg) {
            float f0 = kf(acc[ti][0][reg], (unsigned)((0 << 4) | l15));
            float f1 = kf(acc[ti][1][reg], (unsigned)((1 << 4) | l15));
            float f2 = kf(acc[ti][2][reg], (unsigned)((2 << 4) | l15));
            float f3 = kf(acc[ti][3][reg], (unsigned)((3 << 4) | l15));
            float fk = fmaxf(fmaxf(f0, f1), fmaxf(f2, f3));
            fk = fmax_ror<0x121>(fk);   // ror 1
            fk = fmax_ror<0x122>(fk);   // ror 2
            fk = fmax_ror<0x124>(fk);   // ror 4
            fk = fmax_ror<0x128>(fk);   // ror 8
            if (l15 == 0) {
                unsigned kb = __float_as_uint(fk);
                int grow = rbase + ti * 16 + quad * 4 + reg;
                int col  = cbase + (int)(((kb >> 4) & 3u) * 16u + (kb & 15u));
                unsigned long long gk =
                    ((unsigned long long)(mono_bits(kb) & ~63u) << 32) |
                    (unsigned)col;
                if (cand) cand[(size_t)cb * NROWS + grow] = gk;
                else      atomicMax(&best[grow], gk);
            }
        }
    }

    // Column-direction (off-diagonal blocks): 16 in-lane candidates,
    // then 2 cross-lane maxes; key idx = (ti<<4)|(quad<<2)|reg.
    // Winner for (gcol, tile rb) -> cand[rb][gcol], sole producer.
    if (rb != cb) {
#pragma unroll
        for (int tj = 0; tj < 4; ++tj) {
            float fk = kf(acc[0][tj][0], (unsigned)(quad << 2));
#pragma unroll
            for (int ti = 0; ti < 4; ++ti)
#pragma unroll
                for (int reg = 0; reg < 4; ++reg)
                    if (ti | reg)
                        fk = fmaxf(fk, kf(acc[ti][tj][reg],
                                (unsigned)((ti << 4) | (quad << 2) | reg)));
            fk = fmaxf(fk, __shfl_xor(fk, 16, 64));
            fk = fmaxf(fk, __shfl_xor(fk, 32, 64));
            if (quad == 0) {
                unsigned kb = __float_as_uint(fk);
                int grow = rbase + (int)(((kb >> 4) & 3u) * 16u +
                                         ((kb >> 2) & 3u) * 4u + (kb & 3u));
                int gcol = cbase + tj * 16 + l15;
                unsigned long long gk =
                    ((unsigned long long)(mono_bits(kb) & ~63u) << 32) |
                    (unsigned)grow;
                if (cand) cand[(size_t)rb * NROWS + gcol] = gk;
                else      atomicMax(&best[gcol], gk);
            }
        }
    }
}

// ---------------------------------------------------------------------
// Kernel 2b: best[r] = max over 128 tile-candidates cand[t][r].
// Coalesced: consecutive threads read consecutive r. 16.8 MB ~ 3 us.
// ---------------------------------------------------------------------
__global__ __launch_bounds__(256) void best_reduce_kernel(
    const unsigned long long* __restrict__ cand,
    unsigned long long* __restrict__ best) {
    int r = blockIdx.x * 256 + threadIdx.x;
    unsigned long long m = 0ull;
#pragma unroll 8
    for (int t = 0; t < NTILE; ++t) {
        unsigned long long v = cand[(size_t)t * NROWS + r];
        m = v > m ? v : m;
    }
    best[r] = m;
}

// ---------------------------------------------------------------------
// Kernel 3a: loss from bf16 normalized rows (50 MB vs 100 MB fp32 path)
// ---------------------------------------------------------------------
__global__ __launch_bounds__(256) void loss_bf16_kernel(
    const unsigned* __restrict__ xb,
    const unsigned long long* __restrict__ best,
    float* __restrict__ terms) {
    int wave = threadIdx.x >> 6;
    int lane = threadIdx.x & 63;
    int row  = blockIdx.x * 4 + wave;

    int j = (int)(best[row] & 0xffffffffull);
    const uint2* pi = (const uint2*)(xb + (size_t)row * (DFULL / 2));
    const uint2* pj = (const uint2*)(xb + (size_t)j   * (DFULL / 2));

    float s = 0.0f;
#pragma unroll
    for (int it = 0; it < 3; ++it) {
        int kk = lane + 64 * it;
        uint2 wi = pi[kk], wj = pj[kk];
        float d0 = bf_lo(wi.x) - bf_lo(wj.x) + EPSF;
        float d1 = bf_hi(wi.x) - bf_hi(wj.x) + EPSF;
        float d2 = bf_lo(wi.y) - bf_lo(wj.y) + EPSF;
        float d3 = bf_hi(wi.y) - bf_hi(wj.y) + EPSF;
        s += d0 * d0 + d1 * d1 + d2 * d2 + d3 * d3;
    }
#pragma unroll
    for (int d = 1; d < 64; d <<= 1) s += __shfl_xor(s, d, 64);

    if (lane == 0) terms[row] = logf(sqrtf(s) + EPSF);
}

// ---------------------------------------------------------------------
// Kernel 3b: fallback — loss from fp32 originals (if ws too small)
// ---------------------------------------------------------------------
__global__ __launch_bounds__(256) void loss_kernel(
    const float* __restrict__ a, const float* __restrict__ b,
    const float* __restrict__ invn,
    const unsigned long long* __restrict__ best,
    float* __restrict__ terms) {
    int wave = threadIdx.x >> 6;
    int lane = threadIdx.x & 63;
    int row  = blockIdx.x * 4 + wave;

    int j = (int)(best[row] & 0xffffffffull);
    float ii = invn[row], ij = invn[j];

    const float2* pai = (const float2*)(a + (size_t)row * DHALF);
    const float2* pbi = (const float2*)(b + (size_t)row * DHALF);
    const float2* paj = (const float2*)(a + (size_t)j * DHALF);
    const float2* pbj = (const float2*)(b + (size_t)j * DHALF);

    float s = 0.0f;
#pragma unroll
    for (int it = 0; it < 3; ++it) {
        int kk = lane + 64 * it;
        float2 di = pai[kk], dj = paj[kk];
        float dx = di.x * ii - dj.x * ij + EPSF;
        float dy = di.y * ii - dj.y * ij + EPSF;
        s += dx * dx + dy * dy;
    }
#pragma unroll
    for (int it = 0; it < 3; ++it) {
        int kk = lane + 64 * it;
        float2 di = pbi[kk], dj = pbj[kk];
        float dx = di.x * ii - dj.x * ij + EPSF;
        float dy = di.y * ii - dj.y * ij + EPSF;
        s += dx * dx + dy * dy;
    }
#pragma unroll
    for (int d = 1; d < 64; d <<= 1) s += __shfl_xor(s, d, 64);

    if (lane == 0) terms[row] = logf(sqrtf(s) + EPSF);
}

// ---------------------------------------------------------------------
// Kernel 4: single-block tree reduction of terms -> out[0] = -mean
// ---------------------------------------------------------------------
__global__ __launch_bounds__(1024) void reduce_kernel(
    const float* __restrict__ terms, float* __restrict__ out) {
    __shared__ float partial[16];
    int tid = threadIdx.x;
    float s = 0.0f;
#pragma unroll
    for (int it = 0; it < NROWS / 1024; ++it) s += terms[tid + 1024 * it];
#pragma unroll
    for (int d = 1; d < 64; d <<= 1) s += __shfl_xor(s, d, 64);
    if ((tid & 63) == 0) partial[tid >> 6] = s;
    __syncthreads();
    if (tid < 16) {
        s = partial[tid];
#pragma unroll
        for (int d = 1; d < 16; d <<= 1) s += __shfl_xor(s, d, 16);
        if (tid == 0) out[0] = -s * (1.0f / (float)NROWS);
    }
}

// ---------------------------------------------------------------------
extern "C" void kernel_launch(void* const* d_in, const int* in_sizes, int n_in,
                              void* d_out, int out_size, void* d_ws, size_t ws_size,
                              hipStream_t stream) {
    const float* a = (const float*)d_in[0];
    const float* b = (const float*)d_in[1];
    float* out = (float*)d_out;

    char* ws = (char*)d_ws;
    unsigned char* xq = (unsigned char*)ws;                                    // 6291456 B
    unsigned long long* best = (unsigned long long*)(ws + 6291456);            // 131072 B
    float* invn  = (float*)(ws + 6291456 + 131072);                            // 65536 B
    float* terms = (float*)(ws + 6291456 + 131072 + 65536);                    // 65536 B
    unsigned* xb = (unsigned*)(ws + 6553600);                                  // 25165824 B
    unsigned long long* cand = (unsigned long long*)(ws + 31719424);           // 16777216 B
    const size_t need_xb   = 31719424ull;
    const size_t need_cand = 48496640ull;
    const bool use_xb   = ws_size >= need_xb;     // constant across calls
    const bool use_cand = ws_size >= need_cand;   // constant across calls

    const int NBLK = NTILE * (NTILE + 1) / 2;          // 8256

    normalize_kernel<<<NROWS / 4, 256, 0, stream>>>(
        a, b, xq, invn, best, use_xb ? xb : (unsigned*)nullptr);
    argmax_kernel<<<NBLK, 256, 0, stream>>>(
        xq, best, use_cand ? cand : (unsigned long long*)nullptr);
    if (use_cand)
        best_reduce_kernel<<<NROWS / 256, 256, 0, stream>>>(cand, best);
    if (use_xb)
        loss_bf16_kernel<<<NROWS / 4, 256, 0, stream>>>(xb, best, terms);
    else
        loss_kernel<<<NROWS / 4, 256, 0, stream>>>(a, b, invn, best, terms);
    reduce_kernel<<<1, 1024, 0, stream>>>(terms, out);
}